// Round 8
// baseline (985.696 us; speedup 1.0000x reference)
//
#include <hip/hip_runtime.h>
#include <hip/hip_cooperative_groups.h>
#include <cstdint>
#include <cstddef>

namespace cg = cooperative_groups;

#define L_LAYERS 3
#define H_HEADS 8
#define D_EMB 128
#define DKV 16
#define FF_DIM 512
#define B_BATCH 32
#define N_SEQ 512
#define F_INP 16
#define OUT_DIM 3
#define M_ROWS (B_BATCH * N_SEQ)   // 16384

typedef unsigned short ushort_t;
typedef unsigned int uint_t;
typedef __attribute__((ext_vector_type(8))) short short8;
typedef __attribute__((ext_vector_type(4))) float f32x4;
typedef __attribute__((ext_vector_type(16))) float f32x16;

__device__ inline ushort_t f2bf(float x) {   // RNE float->bf16
    union { float f; uint_t u; } v; v.f = x;
    uint_t r = v.u + 0x7fffu + ((v.u >> 16) & 1u);
    return (ushort_t)(r >> 16);
}

__device__ inline uint_t pack2bf(float a, float b) {  // RNE pack: lo=a, hi=b
    union { float f; uint_t u; } ua, ub;
    ua.f = a; ub.f = b;
    uint_t ra = ua.u + 0x7fffu + ((ua.u >> 16) & 1u);
    uint_t rb = ub.u + 0x7fffu + ((ub.u >> 16) & 1u);
    return (ra >> 16) | (rb & 0xffff0000u);
}

__device__ inline void gload16(const void* g, void* l) {
    __builtin_amdgcn_global_load_lds(
        (const __attribute__((address_space(1))) unsigned int*)g,
        (__attribute__((address_space(3))) unsigned int*)l, 16, 0, 0);
}

// preproc unit counts (256 threads per unit)
#define PM_BLK 32768   // (B*N*N)/256
#define RQ_BLK 576     // L*384*128/256
#define TW_BLK 192     // 3*128*128/256
#define T1_BLK 768     // 3*128*512/256
#define T2_BLK 768
#define EM_BLK 8192    // M_ROWS/2
#define PRE_TOTAL (PM_BLK + RQ_BLK + TW_BLK + T1_BLK + T2_BLK + EM_BLK)

struct MegaParams {
    const int* mask; unsigned long long* pm;
    const float* Wq; const float* Wk; const float* Wv; ushort_t* wqkvT;
    const float* Wout; ushort_t* woutT;
    const float* Wff1; ushort_t* wff1T;
    const float* Wff2; ushort_t* wff2T;
    const float* x; const float* We;
    float* hf; ushort_t* hb;
    ushort_t* qkv16; ushort_t* a16;
    const float* bff1; const float* bff2;
    const float* Wp; const float* Wr; const float* br;
    float* pb; float* out;
};

// ---------------- the whole network as ONE cooperative kernel ----------------
// 256 thr/block, LDS 76.8 KB -> 2 blocks/CU, grid <= 512 (grid-stride phases).
__global__ __launch_bounds__(256, 2) void mega(MegaParams P) {
    cg::grid_group grid = cg::this_grid();
    __shared__ __align__(16) ushort_t sm[38400];   // 76.8 KB, carved per phase
    const int bx = blockIdx.x;
    const int gsz = gridDim.x;
    const int tid = threadIdx.x;
    const int w = tid >> 6, L = tid & 63;
    const int lr = L & 15, lq = L >> 4;
    const int lane31 = L & 31, lhalf = L >> 5;

    // ================= phase 0: preprocessing =================
    for (int g = bx; g < PRE_TOTAL; g += gsz) {
        if (g < PM_BLK) {                        // mask bit-pack
            int gid = g * 256 + tid;
            int v = P.mask[gid];
            unsigned long long bal = __ballot(v != 0);
            if ((tid & 63) == 0) P.pm[gid >> 6] = bal;
        } else if (g < PM_BLK + RQ_BLK) {        // Wq/Wk/Wv -> B^T bf16
            int idx = (g - PM_BLK) * 256 + tid;
            int d = idx & 127;
            int n = (idx >> 7) % 384;
            int l = idx / (384 * 128);
            int proj = n >> 7, hh = (n & 127) >> 4, kk = n & 15;
            const float* src = proj == 0 ? P.Wq : proj == 1 ? P.Wk : P.Wv;
            P.wqkvT[idx] = f2bf(src[((size_t)(l * 8 + hh) * 128 + d) * 16 + kk]);
        } else if (g < PM_BLK + RQ_BLK + TW_BLK + T1_BLK + T2_BLK) {   // transposes
            int gg = g - PM_BLK - RQ_BLK;
            const float* src; ushort_t* dst; int R, C;
            if (gg < TW_BLK) { src = P.Wout; dst = P.woutT; R = 128; C = 128; }
            else if (gg < TW_BLK + T1_BLK) { src = P.Wff1; dst = P.wff1T; R = 128; C = 512; gg -= TW_BLK; }
            else { src = P.Wff2; dst = P.wff2T; R = 512; C = 128; gg -= TW_BLK + T1_BLK; }
            int idx = gg * 256 + tid;
            int b = idx / (R * C);
            int rem = idx - b * (R * C);
            int r = rem / C, c = rem - r * C;
            dst[(size_t)b * R * C + (size_t)c * R + r] = f2bf(src[idx]);
        } else {                                  // embed
            int gg = g - (PRE_TOTAL - EM_BLK);
            const int d = tid & 127;
            const int m = gg * 2 + (tid >> 7);
            const float* xr = P.x + (size_t)m * 16;
            float acc = 0.f;
#pragma unroll
            for (int k = 0; k < 16; k++) acc += xr[k] * P.We[k * 128 + d];
            acc = fmaxf(acc, 0.f);
            P.hf[(size_t)m * 128 + d] = acc;
            P.hb[(size_t)m * 128 + d] = f2bf(acc);
        }
    }
    grid.sync();

    for (int l = 0; l < L_LAYERS; l++) {
        const ushort_t* WqkvT = P.wqkvT + (size_t)l * 384 * 128;
        const ushort_t* WoT = P.woutT + (size_t)l * 128 * 128;
        const ushort_t* W1T = P.wff1T + (size_t)l * 512 * 128;
        const ushort_t* W2T = P.wff2T + (size_t)l * 128 * 512;
        const float* b1 = P.bff1 + l * 512;
        const float* b2 = P.bff2 + l * 128;

        // ================= phase A: QKV GEMM (384 tile-units) =================
        {
            ushort_t* Asm = sm;            // 128*32
            ushort_t* Bsm = sm + 4096;     // 128*32
            const int WM = (w & 1) * 64, WN = (w >> 1) * 64;
            const int sar = w * 16 + (L >> 2);
            const int sac = (L & 3) * 8;
            for (int u = bx; u < 384; u += gsz) {
                const int n0 = (u % 3) * 128, m0 = (u / 3) * 128;
                __syncthreads();
                f32x4 acc[4][4];
#pragma unroll
                for (int i = 0; i < 4; i++)
#pragma unroll
                    for (int j = 0; j < 4; j++) acc[i][j] = (f32x4){0.f, 0.f, 0.f, 0.f};
                for (int k0 = 0; k0 < 128; k0 += 32) {
#pragma unroll
                    for (int it = 0; it < 2; it++)
                        gload16(P.hb + (size_t)(m0 + it * 64 + sar) * 128 + k0 + sac,
                                &Asm[(it * 64 + sar) * 32 + sac]);
#pragma unroll
                    for (int it = 0; it < 2; it++)
                        gload16(WqkvT + (size_t)(n0 + it * 64 + sar) * 128 + k0 + sac,
                                &Bsm[(it * 64 + sar) * 32 + sac]);
                    __syncthreads();
                    short8 af[4], bfr[4];
#pragma unroll
                    for (int i = 0; i < 4; i++)
                        af[i] = *(const short8*)&Asm[(WM + i * 16 + lr) * 32 + lq * 8];
#pragma unroll
                    for (int j = 0; j < 4; j++)
                        bfr[j] = *(const short8*)&Bsm[(WN + j * 16 + lr) * 32 + lq * 8];
#pragma unroll
                    for (int i = 0; i < 4; i++)
#pragma unroll
                        for (int j = 0; j < 4; j++)
                            acc[i][j] = __builtin_amdgcn_mfma_f32_16x16x32_bf16(af[i], bfr[j], acc[i][j], 0, 0, 0);
                    __syncthreads();
                }
                const float qsc = (n0 == 0) ? 0.25f : 1.0f;   // Q prescale
#pragma unroll
                for (int i = 0; i < 4; i++)
#pragma unroll
                    for (int r = 0; r < 4; r++) {
                        const int m = m0 + WM + i * 16 + lq * 4 + r;
#pragma unroll
                        for (int j = 0; j < 4; j++) {
                            const int n = n0 + WN + j * 16 + lr;
                            P.qkv16[(size_t)m * 384 + n] = f2bf(acc[i][j][r] * qsc);
                        }
                    }
            }
        }
        grid.sync();

        // ================= phase B: flash attention (512 units = b,h,half) =================
        {
            ushort_t* KF = sm;                 // 16*512
            ushort_t* Vt = sm + 8192;          // 16*520
            ushort_t* Ps = sm + 16512 + w * 1152;   // per-wave 32*36
            const f32x16 zero16 = (f32x16)(0.f);
            for (int u = bx; u < 512; u += gsz) {
                const int b = u >> 4, h = (u >> 1) & 7, hlf = u & 1;
                const size_t base = (size_t)b * 512 * 384;
                __syncthreads();
#pragma unroll
                for (int i = 0; i < 4; i++) {
                    const int t = i * 4 + w;
                    gload16(P.qkv16 + base + (size_t)(t * 32 + lane31) * 384 + 128 + h * 16 + lhalf * 8,
                            &KF[t * 512 + L * 8]);
                }
#pragma unroll
                for (int i = 0; i < 2; i++) {
                    const int row = i * 256 + tid;
                    const ushort_t* gv = P.qkv16 + base + (size_t)row * 384 + 256 + h * 16;
                    ushort_t tmp[16];
                    *(uint4*)tmp = *(const uint4*)gv;
                    *(uint4*)(tmp + 8) = *(const uint4*)(gv + 8);
#pragma unroll
                    for (int d = 0; d < 16; d++) Vt[d * 520 + row] = tmp[d];
                }
                __syncthreads();
                for (int qt = 0; qt < 2; qt++) {
                    const int q0 = hlf * 256 + w * 64 + qt * 32;
                    const short8 qf = *(const short8*)(P.qkv16 + base + (size_t)(q0 + lane31) * 384 + h * 16 + lhalf * 8);
                    const uint_t* pmr = (const uint_t*)P.pm + (size_t)(b * 512 + q0 + lane31) * 16;
                    const uint4 mwa = *(const uint4*)(pmr);
                    const uint4 mwb = *(const uint4*)(pmr + 4);
                    const uint4 mwc = *(const uint4*)(pmr + 8);
                    const uint4 mwd = *(const uint4*)(pmr + 12);
                    const uint_t mw[16] = {mwa.x, mwa.y, mwa.z, mwa.w, mwb.x, mwb.y, mwb.z, mwb.w,
                                           mwc.x, mwc.y, mwc.z, mwc.w, mwd.x, mwd.y, mwd.z, mwd.w};
                    float mx = -1e30f;
#pragma unroll
                    for (int t = 0; t < 16; t++) {
                        short8 kf = *(const short8*)&KF[t * 512 + L * 8];
                        f32x16 s = __builtin_amdgcn_mfma_f32_32x32x16_bf16(kf, qf, zero16, 0, 0, 0);
#pragma unroll
                        for (int r = 0; r < 16; r++) mx = fmaxf(mx, s[r]);
                    }
                    mx = fmaxf(mx, __shfl_xor(mx, 32));

                    float lsum = 0.f;
                    f32x4 oacc0 = (f32x4){0.f, 0.f, 0.f, 0.f};
                    f32x4 oacc1 = (f32x4){0.f, 0.f, 0.f, 0.f};
#pragma unroll
                    for (int t = 0; t < 16; t++) {
                        short8 kf = *(const short8*)&KF[t * 512 + L * 8];
                        f32x16 s = __builtin_amdgcn_mfma_f32_32x32x16_bf16(kf, qf, zero16, 0, 0, 0);
                        const uint_t word = mw[t];
#pragma unroll
                        for (int r = 0; r < 16; r++) {
                            const int keyl = (r & 3) + 8 * (r >> 2) + 4 * lhalf;
                            const float e = __expf(s[r] - mx);
                            const float pv = (word & (1u << keyl)) ? e : 0.f;
                            s[r] = pv;
                            lsum += pv;
                        }
#pragma unroll
                        for (int g2 = 0; g2 < 4; g2++) {
                            const uint_t lo = pack2bf(s[g2 * 4 + 0], s[g2 * 4 + 1]);
                            const uint_t hi = pack2bf(s[g2 * 4 + 2], s[g2 * 4 + 3]);
                            *(uint2*)&Ps[lane31 * 36 + g2 * 8 + 4 * lhalf] = make_uint2(lo, hi);
                        }
                        short8 vb = *(const short8*)&Vt[lr * 520 + t * 32 + lq * 8];
                        short8 pa0 = *(const short8*)&Ps[lr * 36 + lq * 8];
                        short8 pa1 = *(const short8*)&Ps[(16 + lr) * 36 + lq * 8];
                        oacc0 = __builtin_amdgcn_mfma_f32_16x16x32_bf16(pa0, vb, oacc0, 0, 0, 0);
                        oacc1 = __builtin_amdgcn_mfma_f32_16x16x32_bf16(pa1, vb, oacc1, 0, 0, 0);
                    }
                    lsum += __shfl_xor(lsum, 32);
#pragma unroll
                    for (int qa = 0; qa < 2; qa++) {
                        const f32x4 oa = qa ? oacc1 : oacc0;
#pragma unroll
                        for (int rr = 0; rr < 4; rr++) {
                            const int qloc = qa * 16 + lq * 4 + rr;
                            const float ls = __shfl(lsum, qloc, 64);
                            P.a16[(size_t)(b * 512 + q0 + qloc) * 128 + h * 16 + lr] = f2bf(oa[rr] / ls);
                        }
                    }
                }
            }
        }
        grid.sync();

        // ================= phase C: fused tail (512 units of 32 rows) =================
        {
            ushort_t* As  = sm;            // 32*32
            ushort_t* Bs  = sm + 1024;     // 512*32
            ushort_t* C1b = sm + 17408;    // 32*136
            ushort_t* T   = sm + 21760;    // 32*520
            const int srow = (L >> 2);
            const int scol = (L & 3) * 8;
            for (int u = bx; u < 512; u += gsz) {
                const int m0 = u * 32;
                __syncthreads();
                // ---- A: C1 = a16 @ WoT^T + h ----
                f32x4 c1a[2][2];
#pragma unroll
                for (int i = 0; i < 2; i++)
#pragma unroll
                    for (int j = 0; j < 2; j++) c1a[i][j] = (f32x4){0.f, 0.f, 0.f, 0.f};
                for (int k0 = 0; k0 < 128; k0 += 32) {
                    if (w < 2)
                        gload16(P.a16 + (size_t)(m0 + w * 16 + srow) * 128 + k0 + scol,
                                &As[(w * 16 + srow) * 32 + scol]);
#pragma unroll
                    for (int it = 0; it < 2; it++)
                        gload16(WoT + (size_t)(it * 64 + w * 16 + srow) * 128 + k0 + scol,
                                &Bs[(it * 64 + w * 16 + srow) * 32 + scol]);
                    __syncthreads();
                    short8 af[2], bfr[2];
#pragma unroll
                    for (int i = 0; i < 2; i++) af[i] = *(const short8*)&As[(i * 16 + lr) * 32 + lq * 8];
#pragma unroll
                    for (int j = 0; j < 2; j++) bfr[j] = *(const short8*)&Bs[(w * 32 + j * 16 + lr) * 32 + lq * 8];
#pragma unroll
                    for (int i = 0; i < 2; i++)
#pragma unroll
                        for (int j = 0; j < 2; j++)
                            c1a[i][j] = __builtin_amdgcn_mfma_f32_16x16x32_bf16(af[i], bfr[j], c1a[i][j], 0, 0, 0);
                    __syncthreads();
                }
                float c1[2][2][4];
#pragma unroll
                for (int i = 0; i < 2; i++)
#pragma unroll
                    for (int r = 0; r < 4; r++) {
                        const int row = i * 16 + lq * 4 + r;
#pragma unroll
                        for (int j = 0; j < 2; j++) {
                            const int n = w * 32 + j * 16 + lr;
                            const float v = c1a[i][j][r] + P.hf[(size_t)(m0 + row) * 128 + n];
                            c1[i][j][r] = v;
                            C1b[row * 136 + n] = f2bf(v);
                        }
                    }
                __syncthreads();
                // ---- B: T = relu(C1 @ W1T^T + b1) ----
                f32x4 ta[2][8];
#pragma unroll
                for (int i = 0; i < 2; i++)
#pragma unroll
                    for (int j = 0; j < 8; j++) ta[i][j] = (f32x4){0.f, 0.f, 0.f, 0.f};
                for (int k0 = 0; k0 < 128; k0 += 32) {
#pragma unroll
                    for (int it = 0; it < 8; it++)
                        gload16(W1T + (size_t)(it * 64 + w * 16 + srow) * 128 + k0 + scol,
                                &Bs[(it * 64 + w * 16 + srow) * 32 + scol]);
                    __syncthreads();
                    short8 af[2], bfr[8];
#pragma unroll
                    for (int i = 0; i < 2; i++) af[i] = *(const short8*)&C1b[(i * 16 + lr) * 136 + k0 + lq * 8];
#pragma unroll
                    for (int j = 0; j < 8; j++) bfr[j] = *(const short8*)&Bs[(w * 128 + j * 16 + lr) * 32 + lq * 8];
#pragma unroll
                    for (int i = 0; i < 2; i++)
#pragma unroll
                        for (int j = 0; j < 8; j++)
                            ta[i][j] = __builtin_amdgcn_mfma_f32_16x16x32_bf16(af[i], bfr[j], ta[i][j], 0, 0, 0);
                    __syncthreads();
                }
#pragma unroll
                for (int j = 0; j < 8; j++) {
                    const int n = w * 128 + j * 16 + lr;
                    const float bv = b1[n];
#pragma unroll
                    for (int i = 0; i < 2; i++)
#pragma unroll
                        for (int r = 0; r < 4; r++) {
                            const int row = i * 16 + lq * 4 + r;
                            T[row * 520 + n] = f2bf(fmaxf(ta[i][j][r] + bv, 0.f));
                        }
                }
                __syncthreads();
                // ---- C: h' = C1 + T @ W2T^T + b2 ----
                f32x4 oa[2][2];
#pragma unroll
                for (int i = 0; i < 2; i++)
#pragma unroll
                    for (int j = 0; j < 2; j++) oa[i][j] = (f32x4){0.f, 0.f, 0.f, 0.f};
                for (int k0 = 0; k0 < 512; k0 += 32) {
#pragma unroll
                    for (int it = 0; it < 2; it++)
                        gload16(W2T + (size_t)(it * 64 + w * 16 + srow) * 512 + k0 + scol,
                                &Bs[(it * 64 + w * 16 + srow) * 32 + scol]);
                    __syncthreads();
                    short8 af[2], bfr[2];
#pragma unroll
                    for (int i = 0; i < 2; i++) af[i] = *(const short8*)&T[(i * 16 + lr) * 520 + k0 + lq * 8];
#pragma unroll
                    for (int j = 0; j < 2; j++) bfr[j] = *(const short8*)&Bs[(w * 32 + j * 16 + lr) * 32 + lq * 8];
#pragma unroll
                    for (int i = 0; i < 2; i++)
#pragma unroll
                        for (int j = 0; j < 2; j++)
                            oa[i][j] = __builtin_amdgcn_mfma_f32_16x16x32_bf16(af[i], bfr[j], oa[i][j], 0, 0, 0);
                    __syncthreads();
                }
#pragma unroll
                for (int j = 0; j < 2; j++) {
                    const int n = w * 32 + j * 16 + lr;
                    const float bv = b2[n];
#pragma unroll
                    for (int i = 0; i < 2; i++)
#pragma unroll
                        for (int r = 0; r < 4; r++) {
                            const int row = i * 16 + lq * 4 + r;
                            const float v = oa[i][j][r] + bv + c1[i][j][r];
                            P.hf[(size_t)(m0 + row) * 128 + n] = v;
                            P.hb[(size_t)(m0 + row) * 128 + n] = f2bf(v);
                        }
                }
            }
        }
        grid.sync();
    }

    // ================= phase D: pooled readout (32 units) =================
    if (bx < 32) {
        const int b = bx;
        const int d = tid & 127, g = tid >> 7;   // g in {0,1}
        float* part = (float*)sm;                // [2][128]
        float* pooled = part + 256;
        float* rp = pooled + 128;
        float acc = 0.f;
        const float* hbp = P.hf + (size_t)b * 512 * 128;
        for (int n = g; n < 512; n += 2) acc += hbp[n * 128 + d];
        part[g * 128 + d] = acc;
        __syncthreads();
        if (tid < 128) pooled[tid] = (part[tid] + part[128 + tid]) * (1.0f / 512.0f);
        __syncthreads();
        float a2 = 0.f;
        for (int dd = g * 64; dd < g * 64 + 64; dd++) a2 += pooled[dd] * P.Wp[dd * 128 + d];
        part[g * 128 + d] = a2;
        __syncthreads();
        if (tid < 128) rp[tid] = fmaxf(part[tid] + part[128 + tid], 0.f);
        __syncthreads();
        if (tid < OUT_DIM) {
            float a = P.br[tid];
            for (int jj = 0; jj < 128; jj++) a += rp[jj] * P.Wr[jj * 3 + tid];
            P.pb[b * 3 + tid] = a;
        }
    }
    grid.sync();

    // ================= phase E: final readout (512 units of 32 rows) =================
    for (int u = bx; u < 512; u += gsz) {
        const int row = u * 32 + (tid >> 3);
        const int j = tid & 7;
        const float* hr = P.hf + (size_t)row * 128 + j * 16;
        float a0 = 0.f, a1 = 0.f, a2 = 0.f;
#pragma unroll
        for (int d = 0; d < 16; d++) {
            const float v = fmaxf(hr[d], 0.f);
            const float* wr = P.Wr + (size_t)(128 + j * 16 + d) * 3;
            a0 += v * wr[0]; a1 += v * wr[1]; a2 += v * wr[2];
        }
#pragma unroll
        for (int off = 4; off; off >>= 1) {
            a0 += __shfl_down(a0, off, 8);
            a1 += __shfl_down(a1, off, 8);
            a2 += __shfl_down(a2, off, 8);
        }
        if (j == 0) {
            const int b = row >> 9;
            P.out[(size_t)row * 3 + 0] = a0 + P.pb[b * 3 + 0];
            P.out[(size_t)row * 3 + 1] = a1 + P.pb[b * 3 + 1];
            P.out[(size_t)row * 3 + 2] = a2 + P.pb[b * 3 + 2];
        }
    }
}

extern "C" void kernel_launch(void* const* d_in, const int* in_sizes, int n_in,
                              void* d_out, int out_size, void* d_ws, size_t ws_size,
                              hipStream_t stream) {
    char* ws = (char*)d_ws;
    MegaParams P;
    P.mask = (const int*)d_in[1];
    P.Wq = (const float*)d_in[3]; P.Wk = (const float*)d_in[4]; P.Wv = (const float*)d_in[5];
    P.Wout = (const float*)d_in[6];
    P.Wff1 = (const float*)d_in[7]; P.bff1 = (const float*)d_in[8];
    P.Wff2 = (const float*)d_in[9]; P.bff2 = (const float*)d_in[10];
    P.x = (const float*)d_in[0]; P.We = (const float*)d_in[2];
    P.Wp = (const float*)d_in[11]; P.Wr = (const float*)d_in[12]; P.br = (const float*)d_in[13];
    P.pm    = (unsigned long long*)(ws + 0);        // 1 MiB
    P.wqkvT = (ushort_t*)(ws + 1048576);            // 288 KiB
    P.woutT = (ushort_t*)(ws + 1343488);            // 96 KiB
    P.wff1T = (ushort_t*)(ws + 1441792);            // 384 KiB
    P.wff2T = (ushort_t*)(ws + 1835008);            // 384 KiB
    P.pb    = (float*)(ws + 2228224);               // 384 B
    P.hf    = (float*)(ws + 4194304);               // 8 MiB fp32 residual
    P.hb    = (ushort_t*)(ws + 12582912);           // 4 MiB bf16 mirror
    P.qkv16 = (ushort_t*)(ws + 16777216);           // 12 MiB
    P.a16   = (ushort_t*)(ws + 41943040);           // 4 MiB
    P.out   = (float*)d_out;

    int nb = 0;
    if (hipOccupancyMaxActiveBlocksPerMultiprocessor(&nb, (const void*)mega, 256, 0) != hipSuccess || nb < 1)
        nb = 1;
    int gridsz = nb * 256;
    if (gridsz > 512) gridsz = 512;

    void* args[] = { &P };
    hipLaunchCooperativeKernel((const void*)mega, dim3(gridsz), dim3(256), args, 0, stream);
}

// Round 9
// 437.424 us; speedup vs baseline: 2.2534x; 2.2534x over previous
//
#include <hip/hip_runtime.h>
#include <cstdint>
#include <cstddef>

#define L_LAYERS 3
#define H_HEADS 8
#define D_EMB 128
#define DKV 16
#define FF_DIM 512
#define B_BATCH 32
#define N_SEQ 512
#define F_INP 16
#define OUT_DIM 3
#define M_ROWS (B_BATCH * N_SEQ)   // 16384

typedef unsigned short ushort_t;
typedef unsigned int uint_t;
typedef __attribute__((ext_vector_type(8))) short short8;
typedef __attribute__((ext_vector_type(4))) float f32x4;
typedef __attribute__((ext_vector_type(16))) float f32x16;

__device__ inline ushort_t f2bf(float x) {   // RNE float->bf16
    union { float f; uint_t u; } v; v.f = x;
    uint_t r = v.u + 0x7fffu + ((v.u >> 16) & 1u);
    return (ushort_t)(r >> 16);
}

__device__ inline uint_t pack2bf(float a, float b) {  // RNE pack: lo=a, hi=b
    union { float f; uint_t u; } ua, ub;
    ua.f = a; ub.f = b;
    uint_t ra = ua.u + 0x7fffu + ((ua.u >> 16) & 1u);
    uint_t rb = ub.u + 0x7fffu + ((ub.u >> 16) & 1u);
    return (ra >> 16) | (rb & 0xffff0000u);
}

__device__ inline void gload16(const void* g, void* l) {
    __builtin_amdgcn_global_load_lds(
        (const __attribute__((address_space(1))) unsigned int*)g,
        (__attribute__((address_space(3))) unsigned int*)l, 16, 0, 0);
}

// ---------------- fused preprocessing (unchanged from R7) ----------------
#define PM_BLK 32768
#define RQ_BLK 576
#define TW_BLK 192
#define T1_BLK 768
#define T2_BLK 768
#define EM_BLK 8192
__global__ __launch_bounds__(256) void preproc_kernel(
        const int* __restrict__ mask, unsigned long long* __restrict__ pm,
        const float* __restrict__ Wq, const float* __restrict__ Wk,
        const float* __restrict__ Wv, ushort_t* __restrict__ wqkvT,
        const float* __restrict__ Wout, ushort_t* __restrict__ woutT,
        const float* __restrict__ Wff1, ushort_t* __restrict__ wff1T,
        const float* __restrict__ Wff2, ushort_t* __restrict__ wff2T,
        const float* __restrict__ x, const float* __restrict__ We,
        float* __restrict__ hf, ushort_t* __restrict__ hb) {
    int bx = blockIdx.x;
    const int tid = threadIdx.x;
    if (bx < PM_BLK) {
        int gid = bx * 256 + tid;
        int v = mask[gid];
        unsigned long long bal = __ballot(v != 0);
        if ((tid & 63) == 0) pm[gid >> 6] = bal;
        return;
    }
    bx -= PM_BLK;
    if (bx < RQ_BLK) {
        int idx = bx * 256 + tid;
        int d = idx & 127;
        int n = (idx >> 7) % 384;
        int l = idx / (384 * 128);
        int proj = n >> 7, hh = (n & 127) >> 4, kk = n & 15;
        const float* src = proj == 0 ? Wq : proj == 1 ? Wk : Wv;
        wqkvT[idx] = f2bf(src[((size_t)(l * 8 + hh) * 128 + d) * 16 + kk]);
        return;
    }
    bx -= RQ_BLK;
    if (bx < TW_BLK + T1_BLK + T2_BLK) {
        const float* src; ushort_t* dst; int R, C;
        if (bx < TW_BLK) { src = Wout; dst = woutT; R = 128; C = 128; }
        else if (bx < TW_BLK + T1_BLK) { src = Wff1; dst = wff1T; R = 128; C = 512; bx -= TW_BLK; }
        else { src = Wff2; dst = wff2T; R = 512; C = 128; bx -= TW_BLK + T1_BLK; }
        int idx = bx * 256 + tid;
        int b = idx / (R * C);
        int rem = idx - b * (R * C);
        int r = rem / C, c = rem - r * C;
        dst[(size_t)b * R * C + (size_t)c * R + r] = f2bf(src[idx]);
        return;
    }
    bx -= TW_BLK + T1_BLK + T2_BLK;
    {
        const int d = tid & 127;
        const int m = bx * 2 + (tid >> 7);
        const float* xr = x + (size_t)m * 16;
        float acc = 0.f;
#pragma unroll
        for (int k = 0; k < 16; k++) acc += xr[k] * We[k * 128 + d];
        acc = fmaxf(acc, 0.f);
        hf[(size_t)m * 128 + d] = acc;
        hb[(size_t)m * 128 + d] = f2bf(acc);
    }
}

// ---------------- bf16 MFMA GEMM (QKV) — unchanged from R7 ----------------
__global__ __launch_bounds__(256) void gemm_qkv(const ushort_t* __restrict__ A,
                                                const ushort_t* __restrict__ Bt,
                                                ushort_t* __restrict__ Cb) {
    __shared__ __align__(16) ushort_t Asm[128 * 32];
    __shared__ __align__(16) ushort_t Bsm[128 * 32];
    const int tid = threadIdx.x;
    const int w = tid >> 6, l = tid & 63;
    const int m0 = blockIdx.y * 128, n0 = blockIdx.x * 128;
    const int WM = (w & 1) * 64, WN = (w >> 1) * 64;
    const int lr = l & 15, lq = l >> 4;
    const int sar = w * 16 + (l >> 2);
    const int sac = (l & 3) * 8;

    f32x4 acc[4][4];
#pragma unroll
    for (int i = 0; i < 4; i++)
#pragma unroll
        for (int j = 0; j < 4; j++) acc[i][j] = (f32x4){0.f, 0.f, 0.f, 0.f};

    for (int k0 = 0; k0 < 128; k0 += 32) {
#pragma unroll
        for (int it = 0; it < 2; it++)
            gload16(A + (size_t)(m0 + it * 64 + sar) * 128 + k0 + sac,
                    &Asm[(it * 64 + sar) * 32 + sac]);
#pragma unroll
        for (int it = 0; it < 2; it++)
            gload16(Bt + (size_t)(n0 + it * 64 + sar) * 128 + k0 + sac,
                    &Bsm[(it * 64 + sar) * 32 + sac]);
        __syncthreads();
        short8 af[4], bfr[4];
#pragma unroll
        for (int i = 0; i < 4; i++)
            af[i] = *(const short8*)&Asm[(WM + i * 16 + lr) * 32 + lq * 8];
#pragma unroll
        for (int j = 0; j < 4; j++)
            bfr[j] = *(const short8*)&Bsm[(WN + j * 16 + lr) * 32 + lq * 8];
#pragma unroll
        for (int i = 0; i < 4; i++)
#pragma unroll
            for (int j = 0; j < 4; j++)
                acc[i][j] = __builtin_amdgcn_mfma_f32_16x16x32_bf16(af[i], bfr[j], acc[i][j], 0, 0, 0);
        __syncthreads();
    }

    const float qsc = (blockIdx.x == 0) ? 0.25f : 1.0f;
#pragma unroll
    for (int i = 0; i < 4; i++)
#pragma unroll
        for (int r = 0; r < 4; r++) {
            const int m = m0 + WM + i * 16 + lq * 4 + r;
#pragma unroll
            for (int j = 0; j < 4; j++) {
                const int n = n0 + WN + j * 16 + lr;
                Cb[(size_t)m * 384 + n] = f2bf(acc[i][j][r] * qsc);
            }
        }
}

// ---------------- fused attention + layer tail ----------------
// Block = 32 rows (512 blocks x 256 thr = 4 waves), launch_bounds(256,2) -> no spill.
// Attention: per head h (8 iters): stage K (A-frag layout) + V^T in LDS; the 4 waves split
// the 512 keys (128 each); two-pass softmax w/ LDS max/sum/O cross-wave reduction; O written
// to LDS AsL[32][136] bf16 (the tail A-tile). Then tail phases A/B/C as in R7, reading AsL.
__global__ __launch_bounds__(256, 2) void attn_tail_kernel(
        const ushort_t* __restrict__ qkv,   // [16384][384] bf16; Q prescaled x0.25
        const uint_t* __restrict__ pm,      // packed mask
        const ushort_t* __restrict__ WoT,   // [128 n][128 k]
        const ushort_t* __restrict__ W1T,   // [512 n][128 k]
        const ushort_t* __restrict__ W2T,   // [128 n][512 k]
        const float* __restrict__ b1, const float* __restrict__ b2,
        float* __restrict__ hf, ushort_t* __restrict__ hb) {
    // LDS carve (ushort units):
    // AsL [32][136] @0 | attn: KF @4352 (16KB) Vt @12544 ([16][520]) Ps @20864 (4x32x36)
    //   Ored @25472 (2048 f32) mred @29568 (128 f32) lred @29824 (128 f32)
    // tail: Bs @4352 (8192 us) C1b @12544 ([32][136]) T @16896 ([32][520])
    __shared__ __align__(16) ushort_t sm[33536];   // 67 KB -> 2 blocks/CU
    ushort_t* AsL = sm;
    ushort_t* KF  = sm + 4352;
    ushort_t* Vt  = sm + 12544;
    ushort_t* Ps  = sm + 20864;
    float*    Ored = (float*)(sm + 25472);
    float*    mred = (float*)(sm + 29568);
    float*    lred = (float*)(sm + 29824);
    ushort_t* Bs  = sm + 4352;
    ushort_t* C1b = sm + 12544;
    ushort_t* T   = sm + 16896;

    const int tid = threadIdx.x;
    const int w = tid >> 6, L = tid & 63;
    const int lr = L & 15, lq = L >> 4;
    const int lane31 = L & 31, lhalf = L >> 5;
    const int srow = (L >> 2);
    const int scol = (L & 3) * 8;
    const int m0 = blockIdx.x * 32;
    const int b = m0 >> 9;
    const size_t base = (size_t)b * 512 * 384;
    const f32x16 zero16 = (f32x16)(0.f);

    // mask words for this lane's q (head-independent): tiles w*4..w*4+3
    const uint4 mq = *(const uint4*)(pm + (size_t)(m0 + lane31) * 16 + w * 4);

    // ================= attention over 8 heads =================
    for (int h = 0; h < 8; h++) {
        __syncthreads();   // KF/Vt free, prev head's reduction reads done
        // stage K in 32x32x16 A-frag layout (16 tiles of 32 keys)
#pragma unroll
        for (int i = 0; i < 4; i++) {
            const int t = i * 4 + w;
            gload16(qkv + base + (size_t)(t * 32 + lane31) * 384 + 128 + h * 16 + lhalf * 8,
                    &KF[t * 512 + L * 8]);
        }
        // stage V^T
#pragma unroll
        for (int i = 0; i < 2; i++) {
            const int row = i * 256 + tid;
            const ushort_t* gv = qkv + base + (size_t)row * 384 + 256 + h * 16;
            ushort_t tmp[16];
            *(uint4*)tmp = *(const uint4*)gv;
            *(uint4*)(tmp + 8) = *(const uint4*)(gv + 8);
#pragma unroll
            for (int d = 0; d < 16; d++) Vt[d * 520 + row] = tmp[d];
        }
        // Q B-frag for this head (global, L2-hot)
        const short8 qf = *(const short8*)(qkv + (size_t)(m0 + lane31) * 384 + h * 16 + lhalf * 8);
        __syncthreads();

        // ---- pass 1: partial max over this wave's 128 keys ----
        float mxp = -1e30f;
#pragma unroll
        for (int tt = 0; tt < 4; tt++) {
            const int t = w * 4 + tt;
            short8 kf = *(const short8*)&KF[t * 512 + L * 8];
            f32x16 s = __builtin_amdgcn_mfma_f32_32x32x16_bf16(kf, qf, zero16, 0, 0, 0);
#pragma unroll
            for (int r = 0; r < 16; r++) mxp = fmaxf(mxp, s[r]);
        }
        mxp = fmaxf(mxp, __shfl_xor(mxp, 32));
        if (lhalf == 0) mred[w * 32 + lane31] = mxp;
        __syncthreads();
        const float mx = fmaxf(fmaxf(mred[lane31], mred[32 + lane31]),
                               fmaxf(mred[64 + lane31], mred[96 + lane31]));

        // ---- pass 2: exp + mask + pack + PV over this wave's 4 key-tiles ----
        float lsum = 0.f;
        f32x4 oacc0 = (f32x4){0.f, 0.f, 0.f, 0.f};
        f32x4 oacc1 = (f32x4){0.f, 0.f, 0.f, 0.f};
#pragma unroll
        for (int tt = 0; tt < 4; tt++) {
            const int t = w * 4 + tt;
            short8 kf = *(const short8*)&KF[t * 512 + L * 8];
            f32x16 s = __builtin_amdgcn_mfma_f32_32x32x16_bf16(kf, qf, zero16, 0, 0, 0);
            const uint_t word = (tt == 0) ? mq.x : (tt == 1) ? mq.y : (tt == 2) ? mq.z : mq.w;
#pragma unroll
            for (int r = 0; r < 16; r++) {
                const int keyl = (r & 3) + 8 * (r >> 2) + 4 * lhalf;
                const float e = __expf(s[r] - mx);
                const float pv = (word & (1u << keyl)) ? e : 0.f;
                s[r] = pv;
                lsum += pv;
            }
#pragma unroll
            for (int g = 0; g < 4; g++) {
                const uint_t lo = pack2bf(s[g * 4 + 0], s[g * 4 + 1]);
                const uint_t hi = pack2bf(s[g * 4 + 2], s[g * 4 + 3]);
                *(uint2*)&Ps[w * 1152 + lane31 * 36 + g * 8 + 4 * lhalf] = make_uint2(lo, hi);
            }
            short8 vb = *(const short8*)&Vt[lr * 520 + t * 32 + lq * 8];
            short8 pa0 = *(const short8*)&Ps[w * 1152 + lr * 36 + lq * 8];
            short8 pa1 = *(const short8*)&Ps[w * 1152 + (16 + lr) * 36 + lq * 8];
            oacc0 = __builtin_amdgcn_mfma_f32_16x16x32_bf16(pa0, vb, oacc0, 0, 0, 0);
            oacc1 = __builtin_amdgcn_mfma_f32_16x16x32_bf16(pa1, vb, oacc1, 0, 0, 0);
        }
        lsum += __shfl_xor(lsum, 32);
        if (lhalf == 0) lred[w * 32 + lane31] = lsum;
        // partial O -> LDS  (C layout: q = lq*4+rr (+16 for oacc1), dv = lr)
#pragma unroll
        for (int rr = 0; rr < 4; rr++) {
            Ored[w * 512 + (lq * 4 + rr) * 16 + lr] = oacc0[rr];
            Ored[w * 512 + (16 + lq * 4 + rr) * 16 + lr] = oacc1[rr];
        }
        __syncthreads();
        // cross-wave reduce + normalize -> AsL
#pragma unroll
        for (int ii = 0; ii < 2; ii++) {
            const int idx = ii * 256 + tid;
            const int q = idx >> 4, dv = idx & 15;
            const float ltot = lred[q] + lred[32 + q] + lred[64 + q] + lred[96 + q];
            const float o = Ored[q * 16 + dv] + Ored[512 + q * 16 + dv]
                          + Ored[1024 + q * 16 + dv] + Ored[1536 + q * 16 + dv];
            AsL[q * 136 + h * 16 + dv] = f2bf(o / ltot);
        }
    }
    __syncthreads();   // AsL complete; attn LDS regions free

    // ================= tail phase A: C1 = AsL @ WoT^T + h =================
    f32x4 c1a[2][2];
#pragma unroll
    for (int i = 0; i < 2; i++)
#pragma unroll
        for (int j = 0; j < 2; j++) c1a[i][j] = (f32x4){0.f, 0.f, 0.f, 0.f};
    for (int k0 = 0; k0 < 128; k0 += 32) {
#pragma unroll
        for (int it = 0; it < 2; it++)
            gload16(WoT + (size_t)(it * 64 + w * 16 + srow) * 128 + k0 + scol,
                    &Bs[(it * 64 + w * 16 + srow) * 32 + scol]);
        __syncthreads();
        short8 af[2], bfr[2];
#pragma unroll
        for (int i = 0; i < 2; i++) af[i] = *(const short8*)&AsL[(i * 16 + lr) * 136 + k0 + lq * 8];
#pragma unroll
        for (int j = 0; j < 2; j++) bfr[j] = *(const short8*)&Bs[(w * 32 + j * 16 + lr) * 32 + lq * 8];
#pragma unroll
        for (int i = 0; i < 2; i++)
#pragma unroll
            for (int j = 0; j < 2; j++)
                c1a[i][j] = __builtin_amdgcn_mfma_f32_16x16x32_bf16(af[i], bfr[j], c1a[i][j], 0, 0, 0);
        __syncthreads();
    }
    float c1[2][2][4];
#pragma unroll
    for (int i = 0; i < 2; i++)
#pragma unroll
        for (int r = 0; r < 4; r++) {
            const int row = i * 16 + lq * 4 + r;
#pragma unroll
            for (int j = 0; j < 2; j++) {
                const int n = w * 32 + j * 16 + lr;
                const float v = c1a[i][j][r] + hf[(size_t)(m0 + row) * 128 + n];
                c1[i][j][r] = v;
                C1b[row * 136 + n] = f2bf(v);
            }
        }
    __syncthreads();

    // ================= tail phase B: T = relu(C1 @ W1T^T + b1), 2 n-chunks =================
#pragma unroll
    for (int nc = 0; nc < 2; nc++) {
        f32x4 ta[2][4];
#pragma unroll
        for (int i = 0; i < 2; i++)
#pragma unroll
            for (int j = 0; j < 4; j++) ta[i][j] = (f32x4){0.f, 0.f, 0.f, 0.f};
        for (int k0 = 0; k0 < 128; k0 += 32) {
#pragma unroll
            for (int it = 0; it < 4; it++)
                gload16(W1T + (size_t)(nc * 256 + it * 64 + w * 16 + srow) * 128 + k0 + scol,
                        &Bs[(it * 64 + w * 16 + srow) * 32 + scol]);
            __syncthreads();
            short8 af[2], bfr[4];
#pragma unroll
            for (int i = 0; i < 2; i++) af[i] = *(const short8*)&C1b[(i * 16 + lr) * 136 + k0 + lq * 8];
#pragma unroll
            for (int j = 0; j < 4; j++) bfr[j] = *(const short8*)&Bs[(w * 64 + j * 16 + lr) * 32 + lq * 8];
#pragma unroll
            for (int i = 0; i < 2; i++)
#pragma unroll
                for (int j = 0; j < 4; j++)
                    ta[i][j] = __builtin_amdgcn_mfma_f32_16x16x32_bf16(af[i], bfr[j], ta[i][j], 0, 0, 0);
            __syncthreads();
        }
#pragma unroll
        for (int j = 0; j < 4; j++) {
            const int n = nc * 256 + w * 64 + j * 16 + lr;
            const float bv = b1[n];
#pragma unroll
            for (int i = 0; i < 2; i++)
#pragma unroll
                for (int r = 0; r < 4; r++) {
                    const int row = i * 16 + lq * 4 + r;
                    T[row * 520 + n] = f2bf(fmaxf(ta[i][j][r] + bv, 0.f));
                }
        }
    }
    __syncthreads();

    // ================= tail phase C: h' = C1 + T @ W2T^T + b2 =================
    f32x4 oa[2][2];
#pragma unroll
    for (int i = 0; i < 2; i++)
#pragma unroll
        for (int j = 0; j < 2; j++) oa[i][j] = (f32x4){0.f, 0.f, 0.f, 0.f};
    for (int k0 = 0; k0 < 512; k0 += 32) {
#pragma unroll
        for (int it = 0; it < 2; it++)
            gload16(W2T + (size_t)(it * 64 + w * 16 + srow) * 512 + k0 + scol,
                    &Bs[(it * 64 + w * 16 + srow) * 32 + scol]);
        __syncthreads();
        short8 af[2], bfr[2];
#pragma unroll
        for (int i = 0; i < 2; i++) af[i] = *(const short8*)&T[(i * 16 + lr) * 520 + k0 + lq * 8];
#pragma unroll
        for (int j = 0; j < 2; j++) bfr[j] = *(const short8*)&Bs[(w * 32 + j * 16 + lr) * 32 + lq * 8];
#pragma unroll
        for (int i = 0; i < 2; i++)
#pragma unroll
            for (int j = 0; j < 2; j++)
                oa[i][j] = __builtin_amdgcn_mfma_f32_16x16x32_bf16(af[i], bfr[j], oa[i][j], 0, 0, 0);
        __syncthreads();
    }
#pragma unroll
    for (int j = 0; j < 2; j++) {
        const int n = w * 32 + j * 16 + lr;
        const float bv = b2[n];
#pragma unroll
        for (int i = 0; i < 2; i++)
#pragma unroll
            for (int r = 0; r < 4; r++) {
                const int row = i * 16 + lq * 4 + r;
                const float v = oa[i][j][r] + bv + c1[i][j][r];
                hf[(size_t)(m0 + row) * 128 + n] = v;
                hb[(size_t)(m0 + row) * 128 + n] = f2bf(v);
            }
    }
}

// ------------- merged readout: pool (per b) + final rows -------------
__global__ __launch_bounds__(256) void readout_kernel(const float* __restrict__ h,
                                                      const float* __restrict__ Wp,
                                                      const float* __restrict__ Wr,
                                                      const float* __restrict__ br,
                                                      float* __restrict__ out) {
    const int b = blockIdx.x, t = threadIdx.x;
    const int d = t & 127, g = t >> 7;   // g in {0,1}
    __shared__ float part[2][128];
    __shared__ float pooled[128];
    __shared__ float rp[128];
    __shared__ float pbs[3];
    float acc = 0.f;
    const float* hbp = h + (size_t)b * 512 * 128;
    for (int n = g; n < 512; n += 2) acc += hbp[n * 128 + d];
    part[g][d] = acc;
    __syncthreads();
    if (t < 128) pooled[t] = (part[0][t] + part[1][t]) * (1.0f / 512.0f);
    __syncthreads();
    float a2 = 0.f;
    for (int dd = g * 64; dd < g * 64 + 64; dd++) a2 += pooled[dd] * Wp[dd * 128 + d];
    part[g][d] = a2;
    __syncthreads();
    if (t < 128) rp[t] = fmaxf(part[0][t] + part[1][t], 0.f);
    __syncthreads();
    if (t < OUT_DIM) {
        float a = br[t];
        for (int j = 0; j < 128; j++) a += rp[j] * Wr[j * 3 + t];
        pbs[t] = a;
    }
    __syncthreads();
    // final rows for this b: 16 groups of 32 rows, 8 lanes per row
    const int j = t & 7;
    for (int it = 0; it < 16; it++) {
        const int row = b * 512 + it * 32 + (t >> 3);
        const float* hr = h + (size_t)row * 128 + j * 16;
        float a0 = 0.f, a1 = 0.f, a2o = 0.f;
#pragma unroll
        for (int dd = 0; dd < 16; dd++) {
            const float v = fmaxf(hr[dd], 0.f);
            const float* wr = Wr + (size_t)(128 + j * 16 + dd) * 3;
            a0 += v * wr[0]; a1 += v * wr[1]; a2o += v * wr[2];
        }
#pragma unroll
        for (int off = 4; off; off >>= 1) {
            a0 += __shfl_down(a0, off, 8);
            a1 += __shfl_down(a1, off, 8);
            a2o += __shfl_down(a2o, off, 8);
        }
        if (j == 0) {
            out[(size_t)row * 3 + 0] = a0 + pbs[0];
            out[(size_t)row * 3 + 1] = a1 + pbs[1];
            out[(size_t)row * 3 + 2] = a2o + pbs[2];
        }
    }
}

extern "C" void kernel_launch(void* const* d_in, const int* in_sizes, int n_in,
                              void* d_out, int out_size, void* d_ws, size_t ws_size,
                              hipStream_t stream) {
    const float* x    = (const float*)d_in[0];
    const int*   mask = (const int*)d_in[1];
    const float* We   = (const float*)d_in[2];
    const float* Wq   = (const float*)d_in[3];
    const float* Wk   = (const float*)d_in[4];
    const float* Wv   = (const float*)d_in[5];
    const float* Wout = (const float*)d_in[6];
    const float* Wff1 = (const float*)d_in[7];
    const float* bff1 = (const float*)d_in[8];
    const float* Wff2 = (const float*)d_in[9];
    const float* bff2 = (const float*)d_in[10];
    const float* Wp   = (const float*)d_in[11];
    const float* Wr   = (const float*)d_in[12];
    const float* br   = (const float*)d_in[13];
    float* out = (float*)d_out;

    char* ws = (char*)d_ws;
    unsigned long long* pm64 = (unsigned long long*)(ws + 0);        // 1 MiB
    const uint_t* pm32       = (const uint_t*)(ws + 0);
    ushort_t* wqkvT = (ushort_t*)(ws + 1048576);
    ushort_t* woutT = (ushort_t*)(ws + 1343488);
    ushort_t* wff1T = (ushort_t*)(ws + 1441792);
    ushort_t* wff2T = (ushort_t*)(ws + 1835008);
    float*    hbuf  = (float*)(ws + 4194304);                        // 8 MiB fp32 residual
    ushort_t* hb16  = (ushort_t*)(ws + 12582912);                    // 4 MiB bf16 mirror
    ushort_t* qkv16 = (ushort_t*)(ws + 16777216);                    // 12 MiB

    preproc_kernel<<<PM_BLK + RQ_BLK + TW_BLK + T1_BLK + T2_BLK + EM_BLK, 256, 0, stream>>>(
        mask, pm64, Wq, Wk, Wv, wqkvT, Wout, woutT, Wff1, wff1T, Wff2, wff2T,
        x, We, hbuf, hb16);

    for (int l = 0; l < L_LAYERS; l++) {
        gemm_qkv<<<dim3(3, M_ROWS / 128), 256, 0, stream>>>(
            hb16, wqkvT + (size_t)l * 384 * 128, qkv16);
        attn_tail_kernel<<<M_ROWS / 32, 256, 0, stream>>>(
            qkv16, pm32,
            woutT + (size_t)l * 128 * 128, wff1T + (size_t)l * 512 * 128,
            wff2T + (size_t)l * 128 * 512, bff1 + l * 512, bff2 + l * 128,
            hbuf, hb16);
    }

    readout_kernel<<<B_BATCH, 256, 0, stream>>>(hbuf, Wp, Wr, br, out);
}

// Round 10
// 391.918 us; speedup vs baseline: 2.5151x; 1.1161x over previous
//
#include <hip/hip_runtime.h>
#include <cstdint>
#include <cstddef>

#define L_LAYERS 3
#define H_HEADS 8
#define D_EMB 128
#define DKV 16
#define FF_DIM 512
#define B_BATCH 32
#define N_SEQ 512
#define F_INP 16
#define OUT_DIM 3
#define M_ROWS (B_BATCH * N_SEQ)   // 16384

typedef unsigned short ushort_t;
typedef unsigned int uint_t;
typedef __attribute__((ext_vector_type(8))) short short8;
typedef __attribute__((ext_vector_type(4))) float f32x4;
typedef __attribute__((ext_vector_type(16))) float f32x16;

__device__ inline ushort_t f2bf(float x) {   // RNE float->bf16
    union { float f; uint_t u; } v; v.f = x;
    uint_t r = v.u + 0x7fffu + ((v.u >> 16) & 1u);
    return (ushort_t)(r >> 16);
}

__device__ inline uint_t pack2bf(float a, float b) {  // RNE pack: lo=a, hi=b
    union { float f; uint_t u; } ua, ub;
    ua.f = a; ub.f = b;
    uint_t ra = ua.u + 0x7fffu + ((ua.u >> 16) & 1u);
    uint_t rb = ub.u + 0x7fffu + ((ub.u >> 16) & 1u);
    return (ra >> 16) | (rb & 0xffff0000u);
}

__device__ inline void gload16(const void* g, void* l) {
    __builtin_amdgcn_global_load_lds(
        (const __attribute__((address_space(1))) unsigned int*)g,
        (__attribute__((address_space(3))) unsigned int*)l, 16, 0, 0);
}

// ---------------- fused preprocessing (unchanged) ----------------
#define PM_BLK 32768
#define RQ_BLK 576
#define TW_BLK 192
#define T1_BLK 768
#define T2_BLK 768
#define EM_BLK 8192
__global__ __launch_bounds__(256) void preproc_kernel(
        const int* __restrict__ mask, unsigned long long* __restrict__ pm,
        const float* __restrict__ Wq, const float* __restrict__ Wk,
        const float* __restrict__ Wv, ushort_t* __restrict__ wqkvT,
        const float* __restrict__ Wout, ushort_t* __restrict__ woutT,
        const float* __restrict__ Wff1, ushort_t* __restrict__ wff1T,
        const float* __restrict__ Wff2, ushort_t* __restrict__ wff2T,
        const float* __restrict__ x, const float* __restrict__ We,
        float* __restrict__ hf, ushort_t* __restrict__ hb) {
    int bx = blockIdx.x;
    const int tid = threadIdx.x;
    if (bx < PM_BLK) {
        int gid = bx * 256 + tid;
        int v = mask[gid];
        unsigned long long bal = __ballot(v != 0);
        if ((tid & 63) == 0) pm[gid >> 6] = bal;
        return;
    }
    bx -= PM_BLK;
    if (bx < RQ_BLK) {
        int idx = bx * 256 + tid;
        int d = idx & 127;
        int n = (idx >> 7) % 384;
        int l = idx / (384 * 128);
        int proj = n >> 7, hh = (n & 127) >> 4, kk = n & 15;
        const float* src = proj == 0 ? Wq : proj == 1 ? Wk : Wv;
        wqkvT[idx] = f2bf(src[((size_t)(l * 8 + hh) * 128 + d) * 16 + kk]);
        return;
    }
    bx -= RQ_BLK;
    if (bx < TW_BLK + T1_BLK + T2_BLK) {
        const float* src; ushort_t* dst; int R, C;
        if (bx < TW_BLK) { src = Wout; dst = woutT; R = 128; C = 128; }
        else if (bx < TW_BLK + T1_BLK) { src = Wff1; dst = wff1T; R = 128; C = 512; bx -= TW_BLK; }
        else { src = Wff2; dst = wff2T; R = 512; C = 128; bx -= TW_BLK + T1_BLK; }
        int idx = bx * 256 + tid;
        int b = idx / (R * C);
        int rem = idx - b * (R * C);
        int r = rem / C, c = rem - r * C;
        dst[(size_t)b * R * C + (size_t)c * R + r] = f2bf(src[idx]);
        return;
    }
    bx -= TW_BLK + T1_BLK + T2_BLK;
    {
        const int d = tid & 127;
        const int m = bx * 2 + (tid >> 7);
        const float* xr = x + (size_t)m * 16;
        float acc = 0.f;
#pragma unroll
        for (int k = 0; k < 16; k++) acc += xr[k] * We[k * 128 + d];
        acc = fmaxf(acc, 0.f);
        hf[(size_t)m * 128 + d] = acc;
        hb[(size_t)m * 128 + d] = f2bf(acc);
    }
}

// ---------------- fused QKV-GEMM + flash attention ----------------
// Block = (b,h,half): 512 blocks x 512 thr (8 waves), LDS 61.7 KB -> 2 blocks/CU.
// Phase 1: per-block QKV slice GEMM (A = hb rows of batch b streamed in 128-row chunks;
//   B = W slice [48][128] staged once). Epilogue scatters K into 32x32x16 A-frag layout
//   (KF), V transposed (Vt), Q x0.25 row-major (Qs, this half's 256 rows only).
// Phase 2: v4 two-pass softmax attention entirely from LDS.
__global__ __launch_bounds__(512, 2) void qkv_attn_kernel(
        const ushort_t* __restrict__ hb,    // [16384][128] bf16
        const ushort_t* __restrict__ WqkvT, // layer slice [384][128] bf16 B^T
        const uint_t* __restrict__ pm,      // packed mask
        ushort_t* __restrict__ Aout) {      // [16384][128] bf16
    __shared__ __align__(16) ushort_t sm[30848];   // 61.7 KB
    ushort_t* Qs  = sm;            // [256][16]
    ushort_t* KF  = sm + 4096;     // 16 tiles * 512
    ushort_t* Vt  = sm + 12288;    // [16][520]
    ushort_t* Ws  = sm + 20608;    // [48][128]           (phase 1)
    ushort_t* Asg = sm + 26752;    // [128][32]           (phase 1)
    ushort_t* Ps  = sm + 20608;    // 8 x 32x36           (phase 2, aliases Ws/Asg)

    const int tid = threadIdx.x;
    const int w = tid >> 6, L = tid & 63;
    const int lr = L & 15, lq = L >> 4;
    const int lane31 = L & 31, lhalf = L >> 5;
    const int bx = blockIdx.x;
    const int b = bx >> 4, h = (bx >> 1) & 7, half = bx & 1;

    // ---- stage W slice [48 rows n][128 k]: n<16:Q, 16..31:K, 32..47:V ----
    for (int i = tid; i < 768; i += 512) {
        const int row = i >> 4, cg = i & 15;
        const int proj = row >> 4, kk = row & 15;
        gload16(WqkvT + (size_t)(proj * 128 + h * 16 + kk) * 128 + cg * 8, &Ws[i * 8]);
    }

    // ---- QKV GEMM over 4 chunks of 128 rows ----
    const ushort_t* Ab = hb + (size_t)b * 512 * 128;
    for (int mc = 0; mc < 4; mc++) {
        f32x4 acc[3];
#pragma unroll
        for (int j = 0; j < 3; j++) acc[j] = (f32x4){0.f, 0.f, 0.f, 0.f};
        for (int k0 = 0; k0 < 128; k0 += 32) {
            gload16(Ab + (size_t)(mc * 128 + (tid >> 2)) * 128 + k0 + (tid & 3) * 8,
                    &Asg[tid * 8]);
            __syncthreads();
            short8 af = *(const short8*)&Asg[(w * 16 + lr) * 32 + lq * 8];
#pragma unroll
            for (int j = 0; j < 3; j++) {
                short8 bf = *(const short8*)&Ws[(j * 16 + lr) * 128 + k0 + lq * 8];
                acc[j] = __builtin_amdgcn_mfma_f32_16x16x32_bf16(af, bf, acc[j], 0, 0, 0);
            }
            __syncthreads();
        }
        // epilogue: C layout col = j*16+lr, row = lq*4+r (within wave's 16-row tile)
        const int rbase = mc * 128 + w * 16 + lq * 4;
#pragma unroll
        for (int r = 0; r < 4; r++) {
            const int key = rbase + r;
            // K (j=1): element (key, dk=lr) -> A-frag home
            KF[(key >> 5) * 512 + ((lr >> 3) * 32 + (key & 31)) * 8 + (lr & 7)] = f2bf(acc[1][r]);
            // V (j=2): Vt[dv=lr][key]
            Vt[lr * 520 + key] = f2bf(acc[2][r]);
        }
        if ((mc >> 1) == half) {   // Q only for this half's rows (wave-uniform branch)
            const int qb = (mc & 1) * 128 + w * 16 + lq * 4;
#pragma unroll
            for (int r = 0; r < 4; r++)
                Qs[(qb + r) * 16 + lr] = f2bf(acc[0][r] * 0.25f);
        }
    }
    __syncthreads();

    // ---- phase 2: v4 attention; wave owns 32 queries ----
    const int q0g = half * 256 + w * 32;   // global query base for this wave
    const short8 qf = *(const short8*)&Qs[(w * 32 + lane31) * 16 + lhalf * 8];
    const uint_t* pmr = pm + (size_t)(b * 512 + q0g + lane31) * 16;
    const uint4 mwa = *(const uint4*)(pmr);
    const uint4 mwb = *(const uint4*)(pmr + 4);
    const uint4 mwc = *(const uint4*)(pmr + 8);
    const uint4 mwd = *(const uint4*)(pmr + 12);
    const uint_t mw[16] = {mwa.x, mwa.y, mwa.z, mwa.w, mwb.x, mwb.y, mwb.z, mwb.w,
                           mwc.x, mwc.y, mwc.z, mwc.w, mwd.x, mwd.y, mwd.z, mwd.w};
    const f32x16 zero16 = (f32x16)(0.f);

    float mx = -1e30f;
#pragma unroll
    for (int t = 0; t < 16; t++) {
        short8 kf = *(const short8*)&KF[t * 512 + L * 8];
        f32x16 s = __builtin_amdgcn_mfma_f32_32x32x16_bf16(kf, qf, zero16, 0, 0, 0);
#pragma unroll
        for (int r = 0; r < 16; r++) mx = fmaxf(mx, s[r]);
    }
    mx = fmaxf(mx, __shfl_xor(mx, 32));

    float lsum = 0.f;
    f32x4 oacc0 = (f32x4){0.f, 0.f, 0.f, 0.f};
    f32x4 oacc1 = (f32x4){0.f, 0.f, 0.f, 0.f};
#pragma unroll
    for (int t = 0; t < 16; t++) {
        short8 kf = *(const short8*)&KF[t * 512 + L * 8];
        f32x16 s = __builtin_amdgcn_mfma_f32_32x32x16_bf16(kf, qf, zero16, 0, 0, 0);
        const uint_t word = mw[t];
#pragma unroll
        for (int r = 0; r < 16; r++) {
            const int keyl = (r & 3) + 8 * (r >> 2) + 4 * lhalf;
            const float e = __expf(s[r] - mx);
            const float pv = (word & (1u << keyl)) ? e : 0.f;
            s[r] = pv;
            lsum += pv;
        }
#pragma unroll
        for (int g = 0; g < 4; g++) {
            const uint_t lo = pack2bf(s[g * 4 + 0], s[g * 4 + 1]);
            const uint_t hi = pack2bf(s[g * 4 + 2], s[g * 4 + 3]);
            *(uint2*)&Ps[w * 1152 + lane31 * 36 + g * 8 + 4 * lhalf] = make_uint2(lo, hi);
        }
        short8 vb = *(const short8*)&Vt[lr * 520 + t * 32 + lq * 8];
        short8 pa0 = *(const short8*)&Ps[w * 1152 + lr * 36 + lq * 8];
        short8 pa1 = *(const short8*)&Ps[w * 1152 + (16 + lr) * 36 + lq * 8];
        oacc0 = __builtin_amdgcn_mfma_f32_16x16x32_bf16(pa0, vb, oacc0, 0, 0, 0);
        oacc1 = __builtin_amdgcn_mfma_f32_16x16x32_bf16(pa1, vb, oacc1, 0, 0, 0);
    }
    lsum += __shfl_xor(lsum, 32);

#pragma unroll
    for (int qa = 0; qa < 2; qa++) {
        const f32x4 oa = qa ? oacc1 : oacc0;
#pragma unroll
        for (int rr = 0; rr < 4; rr++) {
            const int qloc = qa * 16 + lq * 4 + rr;
            const float ls = __shfl(lsum, qloc, 64);
            Aout[(size_t)(b * 512 + q0g + qloc) * 128 + h * 16 + lr] = f2bf(oa[rr] / ls);
        }
    }
}

// ---------------- fused layer tail (R7 verbatim, known-good) ----------------
__global__ __launch_bounds__(256, 2) void tail_kernel(
        const ushort_t* __restrict__ A,     // a16 [16384][128]
        const ushort_t* __restrict__ WoT,   // [128 n][128 k]
        const ushort_t* __restrict__ W1T,   // [512 n][128 k]
        const ushort_t* __restrict__ W2T,   // [128 n][512 k]
        const float* __restrict__ b1,
        const float* __restrict__ b2,
        float* __restrict__ hf, ushort_t* __restrict__ hb) {
    __shared__ __align__(16) ushort_t sm[38400];          // 76.8 KB -> 2 blocks/CU
    ushort_t* As  = sm;
    ushort_t* Bs  = sm + 1024;
    ushort_t* C1b = sm + 17408;
    ushort_t* T   = sm + 21760;

    const int tid = threadIdx.x;
    const int w = tid >> 6, l = tid & 63;
    const int lr = l & 15, lq = l >> 4;
    const int srow = (l >> 2);
    const int scol = (l & 3) * 8;
    const int m0 = blockIdx.x * 32;

    // phase A: C1 = a16 @ WoT^T + h
    f32x4 c1a[2][2];
#pragma unroll
    for (int i = 0; i < 2; i++)
#pragma unroll
        for (int j = 0; j < 2; j++) c1a[i][j] = (f32x4){0.f, 0.f, 0.f, 0.f};
    for (int k0 = 0; k0 < 128; k0 += 32) {
        if (w < 2)
            gload16(A + (size_t)(m0 + w * 16 + srow) * 128 + k0 + scol,
                    &As[(w * 16 + srow) * 32 + scol]);
#pragma unroll
        for (int it = 0; it < 2; it++)
            gload16(WoT + (size_t)(it * 64 + w * 16 + srow) * 128 + k0 + scol,
                    &Bs[(it * 64 + w * 16 + srow) * 32 + scol]);
        __syncthreads();
        short8 af[2], bfr[2];
#pragma unroll
        for (int i = 0; i < 2; i++) af[i] = *(const short8*)&As[(i * 16 + lr) * 32 + lq * 8];
#pragma unroll
        for (int j = 0; j < 2; j++) bfr[j] = *(const short8*)&Bs[(w * 32 + j * 16 + lr) * 32 + lq * 8];
#pragma unroll
        for (int i = 0; i < 2; i++)
#pragma unroll
            for (int j = 0; j < 2; j++)
                c1a[i][j] = __builtin_amdgcn_mfma_f32_16x16x32_bf16(af[i], bfr[j], c1a[i][j], 0, 0, 0);
        __syncthreads();
    }
    float c1[2][2][4];
#pragma unroll
    for (int i = 0; i < 2; i++)
#pragma unroll
        for (int r = 0; r < 4; r++) {
            const int row = i * 16 + lq * 4 + r;
#pragma unroll
            for (int j = 0; j < 2; j++) {
                const int n = w * 32 + j * 16 + lr;
                const float v = c1a[i][j][r] + hf[(size_t)(m0 + row) * 128 + n];
                c1[i][j][r] = v;
                C1b[row * 136 + n] = f2bf(v);
            }
        }
    __syncthreads();

    // phase B: T = relu(C1 @ W1T^T + b1)
    f32x4 ta[2][8];
#pragma unroll
    for (int i = 0; i < 2; i++)
#pragma unroll
        for (int j = 0; j < 8; j++) ta[i][j] = (f32x4){0.f, 0.f, 0.f, 0.f};
    for (int k0 = 0; k0 < 128; k0 += 32) {
#pragma unroll
        for (int it = 0; it < 8; it++)
            gload16(W1T + (size_t)(it * 64 + w * 16 + srow) * 128 + k0 + scol,
                    &Bs[(it * 64 + w * 16 + srow) * 32 + scol]);
        __syncthreads();
        short8 af[2], bfr[8];
#pragma unroll
        for (int i = 0; i < 2; i++) af[i] = *(const short8*)&C1b[(i * 16 + lr) * 136 + k0 + lq * 8];
#pragma unroll
        for (int j = 0; j < 8; j++) bfr[j] = *(const short8*)&Bs[(w * 128 + j * 16 + lr) * 32 + lq * 8];
#pragma unroll
        for (int i = 0; i < 2; i++)
#pragma unroll
            for (int j = 0; j < 8; j++)
                ta[i][j] = __builtin_amdgcn_mfma_f32_16x16x32_bf16(af[i], bfr[j], ta[i][j], 0, 0, 0);
        __syncthreads();
    }
#pragma unroll
    for (int j = 0; j < 8; j++) {
        const int n = w * 128 + j * 16 + lr;
        const float bv = b1[n];
#pragma unroll
        for (int i = 0; i < 2; i++)
#pragma unroll
            for (int r = 0; r < 4; r++) {
                const int row = i * 16 + lq * 4 + r;
                T[row * 520 + n] = f2bf(fmaxf(ta[i][j][r] + bv, 0.f));
            }
    }
    __syncthreads();

    // phase C: h' = C1 + T @ W2T^T + b2
    f32x4 oa[2][2];
#pragma unroll
    for (int i = 0; i < 2; i++)
#pragma unroll
        for (int j = 0; j < 2; j++) oa[i][j] = (f32x4){0.f, 0.f, 0.f, 0.f};
    for (int k0 = 0; k0 < 512; k0 += 32) {
#pragma unroll
        for (int it = 0; it < 2; it++)
            gload16(W2T + (size_t)(it * 64 + w * 16 + srow) * 512 + k0 + scol,
                    &Bs[(it * 64 + w * 16 + srow) * 32 + scol]);
        __syncthreads();
        short8 af[2], bfr[2];
#pragma unroll
        for (int i = 0; i < 2; i++) af[i] = *(const short8*)&T[(i * 16 + lr) * 520 + k0 + lq * 8];
#pragma unroll
        for (int j = 0; j < 2; j++) bfr[j] = *(const short8*)&Bs[(w * 32 + j * 16 + lr) * 32 + lq * 8];
#pragma unroll
        for (int i = 0; i < 2; i++)
#pragma unroll
            for (int j = 0; j < 2; j++)
                oa[i][j] = __builtin_amdgcn_mfma_f32_16x16x32_bf16(af[i], bfr[j], oa[i][j], 0, 0, 0);
        __syncthreads();
    }
#pragma unroll
    for (int j = 0; j < 2; j++) {
        const int n = w * 32 + j * 16 + lr;
        const float bv = b2[n];
#pragma unroll
        for (int i = 0; i < 2; i++)
#pragma unroll
            for (int r = 0; r < 4; r++) {
                const int row = i * 16 + lq * 4 + r;
                const float v = oa[i][j][r] + bv + c1[i][j][r];
                hf[(size_t)(m0 + row) * 128 + n] = v;
                hb[(size_t)(m0 + row) * 128 + n] = f2bf(v);
            }
    }
}

// ------------- merged readout: pool (per b) + final rows -------------
__global__ __launch_bounds__(256) void readout_kernel(const float* __restrict__ h,
                                                      const float* __restrict__ Wp,
                                                      const float* __restrict__ Wr,
                                                      const float* __restrict__ br,
                                                      float* __restrict__ out) {
    const int b = blockIdx.x, t = threadIdx.x;
    const int d = t & 127, g = t >> 7;
    __shared__ float part[2][128];
    __shared__ float pooled[128];
    __shared__ float rp[128];
    __shared__ float pbs[3];
    float acc = 0.f;
    const float* hbp = h + (size_t)b * 512 * 128;
    for (int n = g; n < 512; n += 2) acc += hbp[n * 128 + d];
    part[g][d] = acc;
    __syncthreads();
    if (t < 128) pooled[t] = (part[0][t] + part[1][t]) * (1.0f / 512.0f);
    __syncthreads();
    float a2 = 0.f;
    for (int dd = g * 64; dd < g * 64 + 64; dd++) a2 += pooled[dd] * Wp[dd * 128 + d];
    part[g][d] = a2;
    __syncthreads();
    if (t < 128) rp[t] = fmaxf(part[0][t] + part[1][t], 0.f);
    __syncthreads();
    if (t < OUT_DIM) {
        float a = br[t];
        for (int j = 0; j < 128; j++) a += rp[j] * Wr[j * 3 + t];
        pbs[t] = a;
    }
    __syncthreads();
    const int j = t & 7;
    for (int it = 0; it < 16; it++) {
        const int row = b * 512 + it * 32 + (t >> 3);
        const float* hr = h + (size_t)row * 128 + j * 16;
        float a0 = 0.f, a1 = 0.f, a2o = 0.f;
#pragma unroll
        for (int dd = 0; dd < 16; dd++) {
            const float v = fmaxf(hr[dd], 0.f);
            const float* wr = Wr + (size_t)(128 + j * 16 + dd) * 3;
            a0 += v * wr[0]; a1 += v * wr[1]; a2o += v * wr[2];
        }
#pragma unroll
        for (int off = 4; off; off >>= 1) {
            a0 += __shfl_down(a0, off, 8);
            a1 += __shfl_down(a1, off, 8);
            a2o += __shfl_down(a2o, off, 8);
        }
        if (j == 0) {
            out[(size_t)row * 3 + 0] = a0 + pbs[0];
            out[(size_t)row * 3 + 1] = a1 + pbs[1];
            out[(size_t)row * 3 + 2] = a2o + pbs[2];
        }
    }
}

extern "C" void kernel_launch(void* const* d_in, const int* in_sizes, int n_in,
                              void* d_out, int out_size, void* d_ws, size_t ws_size,
                              hipStream_t stream) {
    const float* x    = (const float*)d_in[0];
    const int*   mask = (const int*)d_in[1];
    const float* We   = (const float*)d_in[2];
    const float* Wq   = (const float*)d_in[3];
    const float* Wk   = (const float*)d_in[4];
    const float* Wv   = (const float*)d_in[5];
    const float* Wout = (const float*)d_in[6];
    const float* Wff1 = (const float*)d_in[7];
    const float* bff1 = (const float*)d_in[8];
    const float* Wff2 = (const float*)d_in[9];
    const float* bff2 = (const float*)d_in[10];
    const float* Wp   = (const float*)d_in[11];
    const float* Wr   = (const float*)d_in[12];
    const float* br   = (const float*)d_in[13];
    float* out = (float*)d_out;

    char* ws = (char*)d_ws;
    unsigned long long* pm64 = (unsigned long long*)(ws + 0);        // 1 MiB
    const uint_t* pm32       = (const uint_t*)(ws + 0);
    ushort_t* wqkvT = (ushort_t*)(ws + 1048576);
    ushort_t* woutT = (ushort_t*)(ws + 1343488);
    ushort_t* wff1T = (ushort_t*)(ws + 1441792);
    ushort_t* wff2T = (ushort_t*)(ws + 1835008);
    float*    hbuf  = (float*)(ws + 4194304);                        // 8 MiB fp32 residual
    ushort_t* hb16  = (ushort_t*)(ws + 12582912);                    // 4 MiB bf16 mirror
    ushort_t* a16   = (ushort_t*)(ws + 41943040);                    // 4 MiB attn out

    preproc_kernel<<<PM_BLK + RQ_BLK + TW_BLK + T1_BLK + T2_BLK + EM_BLK, 256, 0, stream>>>(
        mask, pm64, Wq, Wk, Wv, wqkvT, Wout, woutT, Wff1, wff1T, Wff2, wff2T,
        x, We, hbuf, hb16);

    for (int l = 0; l < L_LAYERS; l++) {
        qkv_attn_kernel<<<512, 512, 0, stream>>>(
            hb16, wqkvT + (size_t)l * 384 * 128, pm32, a16);
        tail_kernel<<<M_ROWS / 32, 256, 0, stream>>>(
            a16, woutT + (size_t)l * 128 * 128, wff1T + (size_t)l * 512 * 128,
            wff2T + (size_t)l * 128 * 512, bff1 + l * 512, bff2 + l * 128,
            hbuf, hb16);
    }

    readout_kernel<<<B_BATCH, 256, 0, stream>>>(hbuf, Wp, Wr, br, out);
}

// Round 11
// 297.265 us; speedup vs baseline: 3.3159x; 1.3184x over previous
//
#include <hip/hip_runtime.h>
#include <cstdint>
#include <cstddef>

#define L_LAYERS 3
#define H_HEADS 8
#define D_EMB 128
#define DKV 16
#define FF_DIM 512
#define B_BATCH 32
#define N_SEQ 512
#define F_INP 16
#define OUT_DIM 3
#define M_ROWS (B_BATCH * N_SEQ)   // 16384

typedef unsigned short ushort_t;
typedef unsigned int uint_t;
typedef __attribute__((ext_vector_type(8))) short short8;
typedef __attribute__((ext_vector_type(4))) float f32x4;
typedef __attribute__((ext_vector_type(16))) float f32x16;

__device__ inline ushort_t f2bf(float x) {   // RNE float->bf16
    union { float f; uint_t u; } v; v.f = x;
    uint_t r = v.u + 0x7fffu + ((v.u >> 16) & 1u);
    return (ushort_t)(r >> 16);
}

__device__ inline uint_t pack2bf(float a, float b) {  // RNE pack: lo=a, hi=b
    union { float f; uint_t u; } ua, ub;
    ua.f = a; ub.f = b;
    uint_t ra = ua.u + 0x7fffu + ((ua.u >> 16) & 1u);
    uint_t rb = ub.u + 0x7fffu + ((ub.u >> 16) & 1u);
    return (ra >> 16) | (rb & 0xffff0000u);
}

__device__ inline void gload16(const void* g, void* l) {
    __builtin_amdgcn_global_load_lds(
        (const __attribute__((address_space(1))) unsigned int*)g,
        (__attribute__((address_space(3))) unsigned int*)l, 16, 0, 0);
}

// ---------------- fused preprocessing (+ pbsum zeroing) ----------------
#define PM_BLK 32768
#define RQ_BLK 576
#define TW_BLK 192
#define T1_BLK 768
#define T2_BLK 768
#define PB_BLK 16      // zero pbsum 32*128 floats
#define EM_BLK 8192
__global__ __launch_bounds__(256) void preproc_kernel(
        const int* __restrict__ mask, unsigned long long* __restrict__ pm,
        const float* __restrict__ Wq, const float* __restrict__ Wk,
        const float* __restrict__ Wv, ushort_t* __restrict__ wqkvT,
        const float* __restrict__ Wout, ushort_t* __restrict__ woutT,
        const float* __restrict__ Wff1, ushort_t* __restrict__ wff1T,
        const float* __restrict__ Wff2, ushort_t* __restrict__ wff2T,
        float* __restrict__ pbsum,
        const float* __restrict__ x, const float* __restrict__ We,
        float* __restrict__ hf, ushort_t* __restrict__ hb) {
    int bx = blockIdx.x;
    const int tid = threadIdx.x;
    if (bx < PM_BLK) {
        int gid = bx * 256 + tid;
        int v = mask[gid];
        unsigned long long bal = __ballot(v != 0);
        if ((tid & 63) == 0) pm[gid >> 6] = bal;
        return;
    }
    bx -= PM_BLK;
    if (bx < RQ_BLK) {
        int idx = bx * 256 + tid;
        int d = idx & 127;
        int n = (idx >> 7) % 384;
        int l = idx / (384 * 128);
        int proj = n >> 7, hh = (n & 127) >> 4, kk = n & 15;
        const float* src = proj == 0 ? Wq : proj == 1 ? Wk : Wv;
        wqkvT[idx] = f2bf(src[((size_t)(l * 8 + hh) * 128 + d) * 16 + kk]);
        return;
    }
    bx -= RQ_BLK;
    if (bx < TW_BLK + T1_BLK + T2_BLK) {
        const float* src; ushort_t* dst; int R, C;
        if (bx < TW_BLK) { src = Wout; dst = woutT; R = 128; C = 128; }
        else if (bx < TW_BLK + T1_BLK) { src = Wff1; dst = wff1T; R = 128; C = 512; bx -= TW_BLK; }
        else { src = Wff2; dst = wff2T; R = 512; C = 128; bx -= TW_BLK + T1_BLK; }
        int idx = bx * 256 + tid;
        int b = idx / (R * C);
        int rem = idx - b * (R * C);
        int r = rem / C, c = rem - r * C;
        dst[(size_t)b * R * C + (size_t)c * R + r] = f2bf(src[idx]);
        return;
    }
    bx -= TW_BLK + T1_BLK + T2_BLK;
    if (bx < PB_BLK) {
        pbsum[bx * 256 + tid] = 0.f;
        return;
    }
    bx -= PB_BLK;
    {
        const int d = tid & 127;
        const int m = bx * 2 + (tid >> 7);
        const float* xr = x + (size_t)m * 16;
        float acc = 0.f;
#pragma unroll
        for (int k = 0; k < 16; k++) acc += xr[k] * We[k * 128 + d];
        acc = fmaxf(acc, 0.f);
        hf[(size_t)m * 128 + d] = acc;
        hb[(size_t)m * 128 + d] = f2bf(acc);
    }
}

// ---------------- fused QKV-GEMM + flash attention (v2: no A staging, fewer barriers) ----------------
// Block = (b,h,half): 512 blocks x 512 thr (8 waves), LDS 59.6 KB -> 2 blocks/CU.
__global__ __launch_bounds__(512, 2) void qkv_attn_kernel(
        const ushort_t* __restrict__ hb,    // [16384][128] bf16
        const ushort_t* __restrict__ WqkvT, // layer slice [384][128] bf16 B^T
        const uint_t* __restrict__ pm,      // packed mask
        ushort_t* __restrict__ Aout) {      // [16384][128] bf16
    __shared__ __align__(16) ushort_t sm[29824];   // 59.6 KB
    ushort_t* Qs  = sm;            // [256][16]
    ushort_t* KF  = sm + 4096;     // 16 tiles * 512
    ushort_t* Vt  = sm + 12288;    // [16][520]
    ushort_t* Ws  = sm + 20608;    // [48][128]   (phase 1)
    ushort_t* Ps  = sm + 20608;    // 8 x 32x36   (phase 2, aliases Ws)

    const int tid = threadIdx.x;
    const int w = tid >> 6, L = tid & 63;
    const int lr = L & 15, lq = L >> 4;
    const int lane31 = L & 31, lhalf = L >> 5;
    const int bx = blockIdx.x;
    const int b = bx >> 4, h = (bx >> 1) & 7, half = bx & 1;

    // ---- stage W slice [48 rows n][128 k]: n<16:Q, 16..31:K, 32..47:V ----
    for (int i = tid; i < 768; i += 512) {
        const int row = i >> 4, cg = i & 15;
        const int proj = row >> 4, kk = row & 15;
        gload16(WqkvT + (size_t)(proj * 128 + h * 16 + kk) * 128 + cg * 8, &Ws[i * 8]);
    }
    __syncthreads();

    // ---- QKV GEMM: A-fragments direct from global (L2-hot hb), no barriers ----
    const ushort_t* Ab = hb + (size_t)b * 512 * 128;
    for (int mc = 0; mc < 4; mc++) {
        f32x4 acc[3];
#pragma unroll
        for (int j = 0; j < 3; j++) acc[j] = (f32x4){0.f, 0.f, 0.f, 0.f};
#pragma unroll
        for (int k0 = 0; k0 < 128; k0 += 32) {
            short8 af = *(const short8*)(Ab + (size_t)(mc * 128 + w * 16 + lr) * 128 + k0 + lq * 8);
#pragma unroll
            for (int j = 0; j < 3; j++) {
                short8 bf = *(const short8*)&Ws[(j * 16 + lr) * 128 + k0 + lq * 8];
                acc[j] = __builtin_amdgcn_mfma_f32_16x16x32_bf16(af, bf, acc[j], 0, 0, 0);
            }
        }
        // epilogue: C layout col = j*16+lr, row = lq*4+r
        const int rbase = mc * 128 + w * 16 + lq * 4;
#pragma unroll
        for (int r = 0; r < 4; r++) {
            const int key = rbase + r;
            KF[(key >> 5) * 512 + ((lr >> 3) * 32 + (key & 31)) * 8 + (lr & 7)] = f2bf(acc[1][r]);
            Vt[lr * 520 + key] = f2bf(acc[2][r]);
        }
        if ((mc >> 1) == half) {
            const int qb = (mc & 1) * 128 + w * 16 + lq * 4;
#pragma unroll
            for (int r = 0; r < 4; r++)
                Qs[(qb + r) * 16 + lr] = f2bf(acc[0][r] * 0.25f);
        }
    }
    __syncthreads();

    // ---- phase 2: v4 attention; wave owns 32 queries ----
    const int q0g = half * 256 + w * 32;
    const short8 qf = *(const short8*)&Qs[(w * 32 + lane31) * 16 + lhalf * 8];
    const uint_t* pmr = pm + (size_t)(b * 512 + q0g + lane31) * 16;
    const uint4 mwa = *(const uint4*)(pmr);
    const uint4 mwb = *(const uint4*)(pmr + 4);
    const uint4 mwc = *(const uint4*)(pmr + 8);
    const uint4 mwd = *(const uint4*)(pmr + 12);
    const uint_t mw[16] = {mwa.x, mwa.y, mwa.z, mwa.w, mwb.x, mwb.y, mwb.z, mwb.w,
                           mwc.x, mwc.y, mwc.z, mwc.w, mwd.x, mwd.y, mwd.z, mwd.w};
    const f32x16 zero16 = (f32x16)(0.f);

    float mx = -1e30f;
#pragma unroll
    for (int t = 0; t < 16; t++) {
        short8 kf = *(const short8*)&KF[t * 512 + L * 8];
        f32x16 s = __builtin_amdgcn_mfma_f32_32x32x16_bf16(kf, qf, zero16, 0, 0, 0);
#pragma unroll
        for (int r = 0; r < 16; r++) mx = fmaxf(mx, s[r]);
    }
    mx = fmaxf(mx, __shfl_xor(mx, 32));

    float lsum = 0.f;
    f32x4 oacc0 = (f32x4){0.f, 0.f, 0.f, 0.f};
    f32x4 oacc1 = (f32x4){0.f, 0.f, 0.f, 0.f};
#pragma unroll
    for (int t = 0; t < 16; t++) {
        short8 kf = *(const short8*)&KF[t * 512 + L * 8];
        f32x16 s = __builtin_amdgcn_mfma_f32_32x32x16_bf16(kf, qf, zero16, 0, 0, 0);
        const uint_t word = mw[t];
#pragma unroll
        for (int r = 0; r < 16; r++) {
            const int keyl = (r & 3) + 8 * (r >> 2) + 4 * lhalf;
            const float e = __expf(s[r] - mx);
            const float pv = (word & (1u << keyl)) ? e : 0.f;
            s[r] = pv;
            lsum += pv;
        }
#pragma unroll
        for (int g = 0; g < 4; g++) {
            const uint_t lo = pack2bf(s[g * 4 + 0], s[g * 4 + 1]);
            const uint_t hi = pack2bf(s[g * 4 + 2], s[g * 4 + 3]);
            *(uint2*)&Ps[w * 1152 + lane31 * 36 + g * 8 + 4 * lhalf] = make_uint2(lo, hi);
        }
        short8 vb = *(const short8*)&Vt[lr * 520 + t * 32 + lq * 8];
        short8 pa0 = *(const short8*)&Ps[w * 1152 + lr * 36 + lq * 8];
        short8 pa1 = *(const short8*)&Ps[w * 1152 + (16 + lr) * 36 + lq * 8];
        oacc0 = __builtin_amdgcn_mfma_f32_16x16x32_bf16(pa0, vb, oacc0, 0, 0, 0);
        oacc1 = __builtin_amdgcn_mfma_f32_16x16x32_bf16(pa1, vb, oacc1, 0, 0, 0);
    }
    lsum += __shfl_xor(lsum, 32);

#pragma unroll
    for (int qa = 0; qa < 2; qa++) {
        const f32x4 oa = qa ? oacc1 : oacc0;
#pragma unroll
        for (int rr = 0; rr < 4; rr++) {
            const int qloc = qa * 16 + lq * 4 + rr;
            const float ls = __shfl(lsum, qloc, 64);
            Aout[(size_t)(b * 512 + q0g + qloc) * 128 + h * 16 + lr] = f2bf(oa[rr] / ls);
        }
    }
}

// ---------------- fused layer tail (+ optional pooled-sum accumulation) ----------------
__global__ __launch_bounds__(256, 2) void tail_kernel(
        const ushort_t* __restrict__ A,     // a16 [16384][128]
        const ushort_t* __restrict__ WoT,   // [128 n][128 k]
        const ushort_t* __restrict__ W1T,   // [512 n][128 k]
        const ushort_t* __restrict__ W2T,   // [128 n][512 k]
        const float* __restrict__ b1,
        const float* __restrict__ b2,
        float* __restrict__ hf, ushort_t* __restrict__ hb,
        float* __restrict__ pbsum, int accum) {
    __shared__ __align__(16) ushort_t sm[38400];          // 76.8 KB -> 2 blocks/CU
    ushort_t* As  = sm;
    ushort_t* Bs  = sm + 1024;
    ushort_t* C1b = sm + 17408;
    ushort_t* T   = sm + 21760;

    const int tid = threadIdx.x;
    const int w = tid >> 6, l = tid & 63;
    const int lr = l & 15, lq = l >> 4;
    const int srow = (l >> 2);
    const int scol = (l & 3) * 8;
    const int m0 = blockIdx.x * 32;

    // phase A: C1 = a16 @ WoT^T + h
    f32x4 c1a[2][2];
#pragma unroll
    for (int i = 0; i < 2; i++)
#pragma unroll
        for (int j = 0; j < 2; j++) c1a[i][j] = (f32x4){0.f, 0.f, 0.f, 0.f};
    for (int k0 = 0; k0 < 128; k0 += 32) {
        if (w < 2)
            gload16(A + (size_t)(m0 + w * 16 + srow) * 128 + k0 + scol,
                    &As[(w * 16 + srow) * 32 + scol]);
#pragma unroll
        for (int it = 0; it < 2; it++)
            gload16(WoT + (size_t)(it * 64 + w * 16 + srow) * 128 + k0 + scol,
                    &Bs[(it * 64 + w * 16 + srow) * 32 + scol]);
        __syncthreads();
        short8 af[2], bfr[2];
#pragma unroll
        for (int i = 0; i < 2; i++) af[i] = *(const short8*)&As[(i * 16 + lr) * 32 + lq * 8];
#pragma unroll
        for (int j = 0; j < 2; j++) bfr[j] = *(const short8*)&Bs[(w * 32 + j * 16 + lr) * 32 + lq * 8];
#pragma unroll
        for (int i = 0; i < 2; i++)
#pragma unroll
            for (int j = 0; j < 2; j++)
                c1a[i][j] = __builtin_amdgcn_mfma_f32_16x16x32_bf16(af[i], bfr[j], c1a[i][j], 0, 0, 0);
        __syncthreads();
    }
    float c1[2][2][4];
#pragma unroll
    for (int i = 0; i < 2; i++)
#pragma unroll
        for (int r = 0; r < 4; r++) {
            const int row = i * 16 + lq * 4 + r;
#pragma unroll
            for (int j = 0; j < 2; j++) {
                const int n = w * 32 + j * 16 + lr;
                const float v = c1a[i][j][r] + hf[(size_t)(m0 + row) * 128 + n];
                c1[i][j][r] = v;
                C1b[row * 136 + n] = f2bf(v);
            }
        }
    __syncthreads();

    // phase B: T = relu(C1 @ W1T^T + b1)
    f32x4 ta[2][8];
#pragma unroll
    for (int i = 0; i < 2; i++)
#pragma unroll
        for (int j = 0; j < 8; j++) ta[i][j] = (f32x4){0.f, 0.f, 0.f, 0.f};
    for (int k0 = 0; k0 < 128; k0 += 32) {
#pragma unroll
        for (int it = 0; it < 8; it++)
            gload16(W1T + (size_t)(it * 64 + w * 16 + srow) * 128 + k0 + scol,
                    &Bs[(it * 64 + w * 16 + srow) * 32 + scol]);
        __syncthreads();
        short8 af[2], bfr[8];
#pragma unroll
        for (int i = 0; i < 2; i++) af[i] = *(const short8*)&C1b[(i * 16 + lr) * 136 + k0 + lq * 8];
#pragma unroll
        for (int j = 0; j < 8; j++) bfr[j] = *(const short8*)&Bs[(w * 128 + j * 16 + lr) * 32 + lq * 8];
#pragma unroll
        for (int i = 0; i < 2; i++)
#pragma unroll
            for (int j = 0; j < 8; j++)
                ta[i][j] = __builtin_amdgcn_mfma_f32_16x16x32_bf16(af[i], bfr[j], ta[i][j], 0, 0, 0);
        __syncthreads();
    }
#pragma unroll
    for (int j = 0; j < 8; j++) {
        const int n = w * 128 + j * 16 + lr;
        const float bv = b1[n];
#pragma unroll
        for (int i = 0; i < 2; i++)
#pragma unroll
            for (int r = 0; r < 4; r++) {
                const int row = i * 16 + lq * 4 + r;
                T[row * 520 + n] = f2bf(fmaxf(ta[i][j][r] + bv, 0.f));
            }
    }
    __syncthreads();

    // phase C: h' = C1 + T @ W2T^T + b2
    f32x4 oa[2][2];
#pragma unroll
    for (int i = 0; i < 2; i++)
#pragma unroll
        for (int j = 0; j < 2; j++) oa[i][j] = (f32x4){0.f, 0.f, 0.f, 0.f};
    for (int k0 = 0; k0 < 512; k0 += 32) {
#pragma unroll
        for (int it = 0; it < 2; it++)
            gload16(W2T + (size_t)(it * 64 + w * 16 + srow) * 512 + k0 + scol,
                    &Bs[(it * 64 + w * 16 + srow) * 32 + scol]);
        __syncthreads();
        short8 af[2], bfr[2];
#pragma unroll
        for (int i = 0; i < 2; i++) af[i] = *(const short8*)&T[(i * 16 + lr) * 520 + k0 + lq * 8];
#pragma unroll
        for (int j = 0; j < 2; j++) bfr[j] = *(const short8*)&Bs[(w * 32 + j * 16 + lr) * 32 + lq * 8];
#pragma unroll
        for (int i = 0; i < 2; i++)
#pragma unroll
            for (int j = 0; j < 2; j++)
                oa[i][j] = __builtin_amdgcn_mfma_f32_16x16x32_bf16(af[i], bfr[j], oa[i][j], 0, 0, 0);
        __syncthreads();
    }
#pragma unroll
    for (int j = 0; j < 2; j++) {
        const int n = w * 32 + j * 16 + lr;
        const float bv = b2[n];
        float psum = 0.f;
#pragma unroll
        for (int i = 0; i < 2; i++)
#pragma unroll
            for (int r = 0; r < 4; r++) {
                const int row = i * 16 + lq * 4 + r;
                const float v = oa[i][j][r] + bv + c1[i][j][r];
                psum += v;
                hf[(size_t)(m0 + row) * 128 + n] = v;
                hb[(size_t)(m0 + row) * 128 + n] = f2bf(v);
            }
        if (accum) {   // pooled-sum accumulation (last layer only)
            psum += __shfl_xor(psum, 16);
            psum += __shfl_xor(psum, 32);
            if (lq == 0) atomicAdd(&pbsum[(m0 >> 9) * 128 + n], psum);
        }
    }
}

// ------------- readout: 512 blocks, 32 rows each; pooled head recomputed per block -------------
__global__ __launch_bounds__(256) void readout_kernel(const float* __restrict__ h,
                                                      const float* __restrict__ pbsum,
                                                      const float* __restrict__ Wp,
                                                      const float* __restrict__ Wr,
                                                      const float* __restrict__ br,
                                                      float* __restrict__ out) {
    const int u = blockIdx.x;       // 0..511
    const int b = u >> 4;
    const int m0 = u * 32;
    const int t = threadIdx.x;
    __shared__ float pooled[128];
    __shared__ float rp[128];
    __shared__ float pb3[3];
    if (t < 128) pooled[t] = pbsum[b * 128 + t] * (1.0f / 512.0f);
    __syncthreads();
    if (t < 128) {
        float a = 0.f;
        for (int dd = 0; dd < 128; dd++) a += pooled[dd] * Wp[dd * 128 + t];
        rp[t] = fmaxf(a, 0.f);
    }
    __syncthreads();
    if (t < OUT_DIM) {
        float a = br[t];
        for (int j = 0; j < 128; j++) a += rp[j] * Wr[j * 3 + t];
        pb3[t] = a;
    }
    __syncthreads();
    const int j = t & 7;
    const int row = m0 + (t >> 3);
    const float* hr = h + (size_t)row * 128 + j * 16;
    float a0 = 0.f, a1 = 0.f, a2o = 0.f;
#pragma unroll
    for (int dd = 0; dd < 16; dd++) {
        const float v = fmaxf(hr[dd], 0.f);
        const float* wr = Wr + (size_t)(128 + j * 16 + dd) * 3;
        a0 += v * wr[0]; a1 += v * wr[1]; a2o += v * wr[2];
    }
#pragma unroll
    for (int off = 4; off; off >>= 1) {
        a0 += __shfl_down(a0, off, 8);
        a1 += __shfl_down(a1, off, 8);
        a2o += __shfl_down(a2o, off, 8);
    }
    if (j == 0) {
        out[(size_t)row * 3 + 0] = a0 + pb3[0];
        out[(size_t)row * 3 + 1] = a1 + pb3[1];
        out[(size_t)row * 3 + 2] = a2o + pb3[2];
    }
}

extern "C" void kernel_launch(void* const* d_in, const int* in_sizes, int n_in,
                              void* d_out, int out_size, void* d_ws, size_t ws_size,
                              hipStream_t stream) {
    const float* x    = (const float*)d_in[0];
    const int*   mask = (const int*)d_in[1];
    const float* We   = (const float*)d_in[2];
    const float* Wq   = (const float*)d_in[3];
    const float* Wk   = (const float*)d_in[4];
    const float* Wv   = (const float*)d_in[5];
    const float* Wout = (const float*)d_in[6];
    const float* Wff1 = (const float*)d_in[7];
    const float* bff1 = (const float*)d_in[8];
    const float* Wff2 = (const float*)d_in[9];
    const float* bff2 = (const float*)d_in[10];
    const float* Wp   = (const float*)d_in[11];
    const float* Wr   = (const float*)d_in[12];
    const float* br   = (const float*)d_in[13];
    float* out = (float*)d_out;

    char* ws = (char*)d_ws;
    unsigned long long* pm64 = (unsigned long long*)(ws + 0);        // 1 MiB
    const uint_t* pm32       = (const uint_t*)(ws + 0);
    ushort_t* wqkvT = (ushort_t*)(ws + 1048576);
    ushort_t* woutT = (ushort_t*)(ws + 1343488);
    ushort_t* wff1T = (ushort_t*)(ws + 1441792);
    ushort_t* wff2T = (ushort_t*)(ws + 1835008);
    float*    pbsum = (float*)(ws + 2228224);                        // 16 KiB pooled sums
    float*    hbuf  = (float*)(ws + 4194304);                        // 8 MiB fp32 residual
    ushort_t* hb16  = (ushort_t*)(ws + 12582912);                    // 4 MiB bf16 mirror
    ushort_t* a16   = (ushort_t*)(ws + 41943040);                    // 4 MiB attn out

    preproc_kernel<<<PM_BLK + RQ_BLK + TW_BLK + T1_BLK + T2_BLK + PB_BLK + EM_BLK, 256, 0, stream>>>(
        mask, pm64, Wq, Wk, Wv, wqkvT, Wout, woutT, Wff1, wff1T, Wff2, wff2T,
        pbsum, x, We, hbuf, hb16);

    for (int l = 0; l < L_LAYERS; l++) {
        qkv_attn_kernel<<<512, 512, 0, stream>>>(
            hb16, wqkvT + (size_t)l * 384 * 128, pm32, a16);
        tail_kernel<<<M_ROWS / 32, 256, 0, stream>>>(
            a16, woutT + (size_t)l * 128 * 128, wff1T + (size_t)l * 512 * 128,
            wff2T + (size_t)l * 128 * 512, bff1 + l * 512, bff2 + l * 128,
            hbuf, hb16, pbsum, (l == L_LAYERS - 1) ? 1 : 0);
    }

    readout_kernel<<<512, 256, 0, stream>>>(hbuf, pbsum, Wp, Wr, br, out);
}